// Round 1
// baseline (351.476 us; speedup 1.0000x reference)
//
#include <hip/hip_runtime.h>
#include <stdint.h>

#define BATCH 16384
#define DDIM  3072
#define NK    300
#define NKP   320
#define NCLS  10

#define BM 64
#define BN 160
#define BK 64
#define KT (DDIM / BK)   // 48

typedef __bf16 bf16x8 __attribute__((ext_vector_type(8)));
typedef float  f32x4  __attribute__((ext_vector_type(4)));

typedef __attribute__((address_space(1))) const void gvoid_as1;
typedef __attribute__((address_space(3))) void lvoid_as3;

__device__ __forceinline__ unsigned f2bf(float f) {
  unsigned u = __float_as_uint(f);
  u += 0x7FFFu + ((u >> 16) & 1u);   // RNE
  return u >> 16;
}
__device__ __forceinline__ unsigned long long pack4bf(float a, float b, float c, float d) {
  unsigned lo = f2bf(a) | (f2bf(b) << 16);
  unsigned hi = f2bf(c) | (f2bf(d) << 16);
  return (unsigned long long)lo | ((unsigned long long)hi << 32);
}

// ---------------------------------------------------------------- prep_w ----
// w5 (300x3072 f32) -> wn bf16 (320x3072, rows 300..319 zero), rw[k]=1/(|w|+eps)
__global__ __launch_bounds__(256) void prep_w_kernel(
    const float* __restrict__ w5, unsigned short* __restrict__ wn,
    float* __restrict__ rw, float* __restrict__ gsum, float* __restrict__ gsq) {
  const int r = blockIdx.x;
  const int t = threadIdx.x;
  if (r == 0) {  // zero stat accumulators (gemm runs after this kernel)
    for (int i = t; i < NKP; i += 256) { gsum[i] = 0.f; gsq[i] = 0.f; }
  }
  unsigned long long* dst = (unsigned long long*)(wn + (size_t)r * DDIM);
  if (r < NK) {
    const float4* src = (const float4*)(w5 + (size_t)r * DDIM);
    float ss = 0.f;
#pragma unroll
    for (int i = 0; i < 3; ++i) {
      float4 v = src[t + i * 256];
      ss += v.x * v.x + v.y * v.y + v.z * v.z + v.w * v.w;
      dst[t + i * 256] = pack4bf(v.x, v.y, v.z, v.w);
    }
#pragma unroll
    for (int m = 1; m <= 32; m <<= 1) ss += __shfl_xor(ss, m, 64);
    __shared__ float red[4];
    if ((t & 63) == 0) red[t >> 6] = ss;
    __syncthreads();
    if (t == 0) {
      float tot = red[0] + red[1] + red[2] + red[3];
      rw[r] = 1.f / (sqrtf(tot) + 1e-12f);
    }
  } else {
#pragma unroll
    for (int i = 0; i < 3; ++i) dst[t + i * 256] = 0ull;
    if (t == 0) rw[r] = 0.f;
  }
}

// ------------------------------------------------------------------ gemm ----
// fc5[m][n] = relu( (x[m]. wn[n]) * rx[m] * rw[n] ), plus per-n sum/sumsq atomics.
// 512 threads = 8 waves: 4 M-waves (16 rows each) x 2 N-waves (80 cols each).
__global__ __launch_bounds__(512, 4) void gemm_kernel(
    const float* __restrict__ x, const unsigned short* __restrict__ wn,
    const float* __restrict__ rw, float* __restrict__ fc5,
    float* __restrict__ gsum, float* __restrict__ gsq) {
  __shared__ alignas(16) unsigned short xs[BM * BK];   // 8 KB, XOR-swizzled
  __shared__ alignas(16) unsigned short wt[BN * BK];   // 20 KB, XOR-swizzled
  __shared__ float rxs[BM];
  __shared__ float bsum[BN], bsq[BN];

  const int tid  = threadIdx.x;
  const int lane = tid & 63;
  const int w    = tid >> 6;       // wave 0..7
  const int wm   = w >> 1;         // M-wave 0..3
  const int wnv  = w & 1;          // N-wave 0..1
  const int m0   = (int)(blockIdx.x >> 1) * BM;
  const int n0   = (int)(blockIdx.x & 1) * BN;

  if (tid < BN) { bsum[tid] = 0.f; bsq[tid] = 0.f; }

  // x staging: thread t handles float4-chunk t (row t>>4) and t+512 (row +32)
  const int xr0 = tid >> 4;        // 0..31
  const int xc4 = tid & 15;        // float4 index within row (16 per row)
  const float* xrow0 = x + (size_t)(m0 + xr0) * DDIM;
  const float* xrow1 = x + (size_t)(m0 + xr0 + 32) * DDIM;
  // LDS byte addr: row*128 + (chunk16 ^ (row&7))*16 + half*8 ; chunk16 = xc4>>1
  const int xb0 = xr0 * 128 + ((((xc4 >> 1) ^ (xr0 & 7)) << 4)) + ((xc4 & 1) << 3);
  const int xb1 = (xr0 + 32) * 128 + ((((xc4 >> 1) ^ (xr0 & 7)) << 4)) + ((xc4 & 1) << 3);

  f32x4 zz = {0.f, 0.f, 0.f, 0.f};
  f32x4 acc[5];
#pragma unroll
  for (int i = 0; i < 5; ++i) acc[i] = zz;
  float ss0 = 0.f, ss1 = 0.f;

  for (int kt = 0; kt < KT; ++kt) {
    // ---- stage x (fp32 -> bf16, accumulate row sumsq) ----
    float4 v0 = *(const float4*)(xrow0 + kt * BK + xc4 * 4);
    float4 v1 = *(const float4*)(xrow1 + kt * BK + xc4 * 4);
    ss0 += v0.x * v0.x + v0.y * v0.y + v0.z * v0.z + v0.w * v0.w;
    ss1 += v1.x * v1.x + v1.y * v1.y + v1.z * v1.z + v1.w * v1.w;
    *(unsigned long long*)((char*)xs + xb0) = pack4bf(v0.x, v0.y, v0.z, v0.w);
    *(unsigned long long*)((char*)xs + xb1) = pack4bf(v1.x, v1.y, v1.z, v1.w);
    // ---- stage w via global_load_lds (linear dest, inverse-swizzled source) ----
    for (int i = w; i < 20; i += 8) {
      int c   = i * 64 + lane;              // 16B chunk id 0..1279
      int row = c >> 3;                     // 8 chunks per row
      int clg = (c & 7) ^ (row & 7);        // logical chunk for this phys slot
      const unsigned short* src = wn + (size_t)(n0 + row) * DDIM + kt * BK + clg * 8;
      __builtin_amdgcn_global_load_lds((gvoid_as1*)src,
                                       (lvoid_as3*)((char*)wt + i * 1024), 16, 0, 0);
    }
    __syncthreads();
    // ---- compute: 2 k-steps x (1 A-frag, 5 B-frags, 5 MFMA) per wave ----
#pragma unroll
    for (int ks = 0; ks < 2; ++ks) {
      const int ra = wm * 16 + (lane & 15);
      const int ca = (ks * 4 + (lane >> 4)) ^ (ra & 7);
      bf16x8 a = *(const bf16x8*)((const char*)xs + ra * 128 + ca * 16);
#pragma unroll
      for (int nf = 0; nf < 5; ++nf) {
        const int rb = wnv * 80 + nf * 16 + (lane & 15);
        const int cb = (ks * 4 + (lane >> 4)) ^ (rb & 7);
        bf16x8 b = *(const bf16x8*)((const char*)wt + rb * 128 + cb * 16);
        acc[nf] = __builtin_amdgcn_mfma_f32_16x16x32_bf16(a, b, acc[nf], 0, 0, 0);
      }
    }
    __syncthreads();
  }

  // ---- inverse x-row norms (16 threads share a row; consecutive lanes) ----
#pragma unroll
  for (int m = 1; m <= 8; m <<= 1) {
    ss0 += __shfl_xor(ss0, m, 64);
    ss1 += __shfl_xor(ss1, m, 64);
  }
  if ((tid & 15) == 0) {
    rxs[xr0]      = 1.f / (sqrtf(ss0) + 1e-12f);
    rxs[xr0 + 32] = 1.f / (sqrtf(ss1) + 1e-12f);
  }
  __syncthreads();

  // ---- epilogue: scale, relu, store, per-channel stats ----
  const int rgrp = lane >> 4;
  const int cl   = lane & 15;
  float rx[4];
#pragma unroll
  for (int j = 0; j < 4; ++j) rx[j] = rxs[wm * 16 + rgrp * 4 + j];
#pragma unroll
  for (int nf = 0; nf < 5; ++nf) {
    const int nl = wnv * 80 + nf * 16 + cl;   // local col 0..159
    const int ng = n0 + nl;                   // global col
    const float rwv = rw[ng];
    float s = 0.f, q = 0.f;
#pragma unroll
    for (int j = 0; j < 4; ++j) {
      float v = acc[nf][j] * rx[j] * rwv;
      v = fmaxf(v, 0.f);
      if (ng < NK) fc5[(size_t)(m0 + wm * 16 + rgrp * 4 + j) * NK + ng] = v;
      s += v; q += v * v;
    }
    s += __shfl_xor(s, 16, 64); s += __shfl_xor(s, 32, 64);
    q += __shfl_xor(q, 16, 64); q += __shfl_xor(q, 32, 64);
    if (rgrp == 0) { atomicAdd(&bsum[nl], s); atomicAdd(&bsq[nl], q); }
  }
  __syncthreads();
  if (tid < BN) {
    const int ng = n0 + tid;
    if (ng < NK) { atomicAdd(&gsum[ng], bsum[tid]); atomicAdd(&gsq[ng], bsq[tid]); }
  }
}

// ---------------------------------------------------------------- bn+fc6 ----
// Finalizes stats per block (redundant, cheap), applies BN, 300->10 readout.
__global__ __launch_bounds__(256) void bn_fc6_kernel(
    const float* __restrict__ fc5, const float* __restrict__ w6,
    const float* __restrict__ gamma, const float* __restrict__ beta,
    const float* __restrict__ gsum, const float* __restrict__ gsq,
    float* __restrict__ bn5, float* __restrict__ fc6) {
  __shared__ float w6s[NCLS * NK];
  __shared__ float scs[NK], shs[NK];
  const int t = threadIdx.x;
  for (int i = t; i < NCLS * NK; i += 256) w6s[i] = w6[i];
  for (int i = t; i < NK; i += 256) {
    const float invB = 1.f / (float)BATCH;
    float mean = gsum[i] * invB;
    float var  = gsq[i] * invB - mean * mean;
    var = fmaxf(var, 0.f);
    float sc = gamma[i] * rsqrtf(var + 1e-5f);
    scs[i] = sc;
    shs[i] = beta[i] - mean * sc;
  }
  __syncthreads();
  const int wv = t >> 6, l = t & 63;
  const int r = (int)blockIdx.x * 4 + wv;
  const float* frow = fc5 + (size_t)r * NK;
  float* brow = bn5 + (size_t)r * NK;
  float accv[NCLS];
#pragma unroll
  for (int o = 0; o < NCLS; ++o) accv[o] = 0.f;
#pragma unroll
  for (int i = 0; i < 5; ++i) {
    const int k = i * 64 + l;
    if (k < NK) {
      float b = frow[k] * scs[k] + shs[k];
      brow[k] = b;
#pragma unroll
      for (int o = 0; o < NCLS; ++o) accv[o] += b * w6s[o * NK + k];
    }
  }
#pragma unroll
  for (int o = 0; o < NCLS; ++o) {
    float v = accv[o];
#pragma unroll
    for (int m = 1; m <= 32; m <<= 1) v += __shfl_xor(v, m, 64);
    if (l == 0) fc6[(size_t)r * NCLS + o] = v;
  }
}

// ---------------------------------------------------------------- launch ----
extern "C" void kernel_launch(void* const* d_in, const int* in_sizes, int n_in,
                              void* d_out, int out_size, void* d_ws, size_t ws_size,
                              hipStream_t stream) {
  const float* x     = (const float*)d_in[0];
  const float* w5    = (const float*)d_in[1];
  const float* gamma = (const float*)d_in[2];
  const float* beta  = (const float*)d_in[3];
  const float* w6    = (const float*)d_in[4];

  float* fc5 = (float*)d_out;
  float* bn5 = fc5 + (size_t)BATCH * NK;
  float* fc6 = bn5 + (size_t)BATCH * NK;

  char* ws = (char*)d_ws;
  unsigned short* wn = (unsigned short*)ws;                 // 320*3072*2 B
  float* rw   = (float*)(ws + (size_t)NKP * DDIM * 2);
  float* gsum = rw + NKP;
  float* gsq  = gsum + NKP;

  hipLaunchKernelGGL(prep_w_kernel, dim3(NKP), dim3(256), 0, stream,
                     w5, wn, rw, gsum, gsq);
  hipLaunchKernelGGL(gemm_kernel, dim3((BATCH / BM) * 2), dim3(512), 0, stream,
                     x, wn, rw, fc5, gsum, gsq);
  hipLaunchKernelGGL(bn_fc6_kernel, dim3(BATCH / 4), dim3(256), 0, stream,
                     fc5, w6, gamma, beta, gsum, gsq, bn5, fc6);
}